// Round 1
// 257.292 us; speedup vs baseline: 1.0210x; 1.0210x over previous
//
#include <hip/hip_runtime.h>
#include <hip/hip_bf16.h>

typedef unsigned short ushort_t;
typedef __attribute__((ext_vector_type(8))) short short8;   // 8 x bf16 (4 VGPRs)
typedef __attribute__((ext_vector_type(4))) float floatx4;  // MFMA acc

#define BATCH 4
#define SEQ   2048
#define CH    1024
#define NHEAD 16
#define HSZ   64
#define MROWS (BATCH * SEQ)  // 8192

// async global->LDS, 16B per lane; LDS dest = wave-uniform base + lane*16
#define GLD16(gptr, lptr) \
    __builtin_amdgcn_global_load_lds((const __attribute__((address_space(1))) unsigned int*)(gptr), \
                                     (__attribute__((address_space(3))) unsigned int*)(lptr), 16, 0, 0)

__device__ inline ushort_t f2b(float f) {
    __hip_bfloat16 h = __float2bfloat16(f);
    return *(ushort_t*)&h;
}
__device__ inline float b2f(ushort_t u) {
    return __bfloat162float(*(__hip_bfloat16*)&u);
}

// -------- dtype detect (parallel): *flag = 1 if x is bf16, 0 if f32 --------------
__global__ void detect_dtype(const ushort_t* __restrict__ x, int* __restrict__ flag) {
    int cnt = 0;
    #pragma unroll
    for (int i = 0; i < 8; i++) {
        const int e = (x[2 * (threadIdx.x * 8 + i)] >> 7) & 0xFF;
        const unsigned long long m = __ballot(e >= 100 && e <= 140);
        cnt += (int)__popcll(m);
    }
    if (threadIdx.x == 0) *flag = (cnt >= 400) ? 1 : 0;
}

// -------- 4x weight transpose+convert: in[k][n] -> out bf16 [n][k] ---------------
__global__ __launch_bounds__(256) void convert_wt4(const void* w0, const void* w1,
                                                   const void* w2, const void* w3,
                                                   ushort_t* o0, ushort_t* o1,
                                                   ushort_t* o2, ushort_t* o3,
                                                   const int* __restrict__ flag) {
    __shared__ ushort_t tile[32][33];
    const void* in = (blockIdx.z == 0) ? w0 : (blockIdx.z == 1) ? w1 : (blockIdx.z == 2) ? w2 : w3;
    ushort_t*  out = (blockIdx.z == 0) ? o0 : (blockIdx.z == 1) ? o1 : (blockIdx.z == 2) ? o2 : o3;
    const int am = *flag;
    const int bx = blockIdx.x * 32, by = blockIdx.y * 32;
    const int tx = threadIdx.x & 31, ty = threadIdx.x >> 5;
    #pragma unroll
    for (int r = ty; r < 32; r += 8) {
        const size_t idx = (size_t)(by + r) * CH + bx + tx;
        tile[r][tx] = am ? ((const ushort_t*)in)[idx] : f2b(((const float*)in)[idx]);
    }
    __syncthreads();
    #pragma unroll
    for (int r = ty; r < 32; r += 8)
        out[(size_t)(bx + r) * CH + by + tx] = tile[tx][r];
}

// -------- 4x bias convert --------------------------------------------------------
__global__ void convert_bias4(const void* b0, const void* b1, const void* b2, const void* b3,
                              ushort_t* __restrict__ out, const int* __restrict__ flag) {
    const int i = blockIdx.x * 256 + threadIdx.x;  // 0..4095
    const int m = i >> 10, idx = i & 1023;
    const void* in = (m == 0) ? b0 : (m == 1) ? b1 : (m == 2) ? b2 : b3;
    out[i] = (*flag) ? ((const ushort_t*)in)[idx] : f2b(((const float*)in)[idx]);
}

// -------- x convert: flat fp32/bf16 -> bf16, 8 elems/thread ----------------------
__global__ __launch_bounds__(256) void convert_x(const void* __restrict__ in,
                                                 ushort_t* __restrict__ out,
                                                 const int* __restrict__ flag) {
    const int i = (blockIdx.x * 256 + threadIdx.x) * 8;
    if (*flag) {
        *(float4*)&out[i] = *(const float4*)&((const ushort_t*)in)[i];
    } else {
        const float* p = (const float*)in + i;
        float4 f0 = *(const float4*)p;
        float4 f1 = *(const float4*)(p + 4);
        ushort_t t[8] = {f2b(f0.x), f2b(f0.y), f2b(f0.z), f2b(f0.w),
                         f2b(f1.x), f2b(f1.y), f2b(f1.z), f2b(f1.w)};
        *(float4*)&out[i] = *(const float4*)t;
    }
}

// -------- BK=64 XOR-swizzled K-loop (shared by both GEMMs) -----------------------
// K=1024 -> 16 iterations (was 32): half the vmcnt(0)+barrier drains, 32 MFMA
// per iteration. 128-B LDS rows would be 16-way bank-conflicted on b128 frag
// reads, so staging XOR-permutes chunks: phys = logical ^ (row&7); reads use
// chunk (kk*4+quad)^(lane15&7) -> 2 lanes/bank = free (m136). LDS 2x16KB=32KB.
__device__ __forceinline__ void kloop64(const ushort_t* __restrict__ A,
                                        const ushort_t* __restrict__ Bt,
                                        int K, int row0, int col0,
                                        ushort_t* As, ushort_t* Bs,
                                        floatx4 acc[4][4],
                                        int lane, int wave) {
    const int lane15 = lane & 15, quad = lane >> 4;
    const int wr = (wave >> 1) * 64, wc = (wave & 1) * 64;
    const int rg = lane >> 3;                       // row within 8-row group
    const int cg = (lane & 7) ^ rg;                 // staged (permuted) chunk
    const int s7 = lane15 & 7;                      // read-side swizzle key
    for (int k0 = 0; k0 < K; k0 += 64) {
        #pragma unroll
        for (int l = wave; l < 16; l += 4) {        // 16 wave-loads each (8 rows x 1KB)
            GLD16(A  + (size_t)(row0 + l * 8 + rg) * K + k0 + cg * 8, &As[l * 512]);
            GLD16(Bt + (size_t)(col0 + l * 8 + rg) * K + k0 + cg * 8, &Bs[l * 512]);
        }
        __syncthreads();
        #pragma unroll
        for (int kk = 0; kk < 2; kk++) {
            short8 af[4], bfr[4];
            #pragma unroll
            for (int i = 0; i < 4; i++)
                af[i] = *(const short8*)&As[(wr + i * 16 + lane15) * 64 + (((kk * 4 + quad) ^ s7) * 8)];
            #pragma unroll
            for (int j = 0; j < 4; j++)
                bfr[j] = *(const short8*)&Bs[(wc + j * 16 + lane15) * 64 + (((kk * 4 + quad) ^ s7) * 8)];
            #pragma unroll
            for (int i = 0; i < 4; i++)
                #pragma unroll
                for (int j = 0; j < 4; j++)
                    acc[i][j] = __builtin_amdgcn_mfma_f32_16x16x32_bf16(af[i], bfr[j], acc[i][j], 0, 0, 0);
        }
        __syncthreads();
    }
}

// ---------------- fused QKV GEMM: [8192,1024] @ [3072,1024]^T + bias -------------
// Column segment (blockIdx.y>>3): 0 -> Qb row-major *qscale; 1 -> Kb row-major;
// 2 -> Vt[b][n][t] transposed-per-head. Branch is block-uniform.
__global__ __launch_bounds__(256) void gemm_qkv(const ushort_t* __restrict__ A,
                                                const ushort_t* __restrict__ Bt,
                                                const ushort_t* __restrict__ bias,
                                                ushort_t* __restrict__ Qb,
                                                ushort_t* __restrict__ Kb,
                                                ushort_t* __restrict__ Vt,
                                                float qscale) {
    __shared__ __align__(16) ushort_t As[128 * 64];
    __shared__ __align__(16) ushort_t Bs[128 * 64];
    const int tid = threadIdx.x;
    const int lane = tid & 63, wave = tid >> 6;
    const int lane15 = lane & 15, quad = lane >> 4;
    const int wr = (wave >> 1) * 64, wc = (wave & 1) * 64;
    const int row0 = blockIdx.x * 128, col0 = blockIdx.y * 128;
    const int seg = blockIdx.y >> 3;  // 0=Q 1=K 2=V

    floatx4 acc[4][4];
    #pragma unroll
    for (int i = 0; i < 4; i++)
        #pragma unroll
        for (int j = 0; j < 4; j++) acc[i][j] = {0.f, 0.f, 0.f, 0.f};

    kloop64(A, Bt, CH, row0, col0, As, Bs, acc, lane, wave);

    #pragma unroll
    for (int j = 0; j < 4; j++) {
        const int col = col0 + wc + j * 16 + lane15;
        const float bv = b2f(bias[col]);
        #pragma unroll
        for (int i = 0; i < 4; i++) {
            const int rowb = row0 + wr + i * 16 + quad * 4;
            if (seg == 0) {
                #pragma unroll
                for (int r = 0; r < 4; r++)
                    Qb[(size_t)(rowb + r) * CH + col] = f2b((acc[i][j][r] + bv) * qscale);
            } else if (seg == 1) {
                const int c = col - 1024;
                #pragma unroll
                for (int r = 0; r < 4; r++)
                    Kb[(size_t)(rowb + r) * CH + c] = f2b(acc[i][j][r] + bv);
            } else {
                const int c = col - 2048;
                ushort_t pk[4];
                #pragma unroll
                for (int r = 0; r < 4; r++) pk[r] = f2b(acc[i][j][r] + bv);
                const int bb = rowb >> 11, t = rowb & 2047;
                *(uint2*)&Vt[((size_t)bb * 1024 + c) * 2048 + t] = *(const uint2*)pk;
            }
        }
    }
}

// ---------------- output GEMM: Out[M,N] = A @ Bt^T + bias (fp32 or bf16 out) -----
__global__ __launch_bounds__(256) void gemm_bt(const ushort_t* __restrict__ A,
                                               const ushort_t* __restrict__ Bt,
                                               const ushort_t* __restrict__ bias,
                                               void* __restrict__ Out,
                                               int M, int N, int K,
                                               const int* __restrict__ oflag) {
    __shared__ __align__(16) ushort_t As[128 * 64];
    __shared__ __align__(16) ushort_t Bs[128 * 64];
    const int om = *oflag;
    const int tid = threadIdx.x;
    const int lane = tid & 63, wave = tid >> 6;
    const int lane15 = lane & 15, quad = lane >> 4;
    const int wr = (wave >> 1) * 64, wc = (wave & 1) * 64;
    const int row0 = blockIdx.x * 128, col0 = blockIdx.y * 128;

    floatx4 acc[4][4];
    #pragma unroll
    for (int i = 0; i < 4; i++)
        #pragma unroll
        for (int j = 0; j < 4; j++) acc[i][j] = {0.f, 0.f, 0.f, 0.f};

    kloop64(A, Bt, K, row0, col0, As, Bs, acc, lane, wave);

    #pragma unroll
    for (int j = 0; j < 4; j++) {
        const int col = col0 + wc + j * 16 + lane15;
        const float bv = b2f(bias[col]);
        #pragma unroll
        for (int i = 0; i < 4; i++) {
            const int rowb = row0 + wr + i * 16 + quad * 4;
            #pragma unroll
            for (int r = 0; r < 4; r++) {
                const float val = acc[i][j][r] + bv;
                const size_t idx = (size_t)(rowb + r) * N + col;
                if (om) ((ushort_t*)Out)[idx] = f2b(val);
                else    ((float*)Out)[idx] = val;
            }
        }
    }
}

// ---------------- flash attention (round-6 structure + S^T write path) -----------
// Ps LDS round-trip decouples the S-phase from PV (overlappable across waves) —
// measured 79-81 us vs 110 us for the register-shuffle S^T form and 240 us for
// the VGPR-clamped variant. Keep: K/V dbuf, one barrier per tile, XCD-local
// (b,h) in bid&63, ones-MFMA rowsum, exp2 with scale folded into Q, swizzled
// K/V staging. DO NOT add a second __launch_bounds__ arg (round-7 spill).
//
// R0 change: S MFMA computes S^T = mfma(K_frag, Q_frag) — a/b fragments have
// identical lane mappings, so the SAME Ks reads + SAME qf registers work with
// operands swapped; zero new loads/shuffles. Output flips to row=kv, col=q:
// each lane's 4 acc values are now 4 CONTIGUOUS kv entries of one Ps row ->
// 2x v_cvt_pk_bf16_f32 (HW RNE pack) + 1x ds_write_b64, replacing 32 scalar
// f2b sequences (~150 VALU cyc/tile) + 32 ds_write_b16 with 16 cvt_pk + 8 b64
// writes. PV reads of Ps[q][kv] are UNCHANGED (this is NOT the 110-us register
// S^T variant — the LDS decoupling stays). Stride-72 bank math: b64 writes =
// 4/bank uniform (b64 minimum, free); b128 reads = 8/bank uniform (free).
__global__ __launch_bounds__(256) void attn_fwd(ushort_t* __restrict__ QY,
                                                const ushort_t* __restrict__ K,
                                                const ushort_t* __restrict__ Vt) {
    __shared__ __align__(16) ushort_t Ks[2][64 * 64];    // [buf][kv][d], swizzled
    __shared__ __align__(16) ushort_t Vs[2][64 * 64];    // [buf][d][kv], swizzled
    __shared__ __align__(16) ushort_t Ps[4 * 32 * 72];   // per-wave [q=32][kv=64], stride 72
    const int tid = threadIdx.x;
    const int lane = tid & 63, wave = tid >> 6;
    const int lane15 = lane & 15, quad = lane >> 4;
    const int sw = lane15 & 7;                            // read-side swizzle key
    const int bid = blockIdx.x;
    const int hb = bid & 63, qslot = bid >> 6;
    const int qb = 15 - qslot;
    const int h = hb & 15, b = hb >> 4;
    const int q0 = qb * 128;
    const size_t baseR = (size_t)b * SEQ * CH + h * HSZ;      // +t*CH+d (Q,K,Y)
    const size_t baseV = ((size_t)b * 1024 + h * HSZ) * SEQ;  // +d*SEQ+t (Vt)
    const int rg = lane >> 3, cg = (lane & 7) ^ rg;           // staging swizzle

    short8 qf[2][2];
    #pragma unroll
    for (int mm = 0; mm < 2; mm++) {
        const ushort_t* qp = QY + baseR + (size_t)(q0 + wave * 32 + mm * 16 + lane15) * CH + quad * 8;
        qf[mm][0] = *(const short8*)qp;
        qf[mm][1] = *(const short8*)(qp + 32);
    }
    const short8 kOnes = (short8)(short)0x3F80;  // bf16 1.0 x8

    floatx4 o[2][5];  // [mm][0..3]=O d-chunks, [4]=l (rowsum)
    #pragma unroll
    for (int mm = 0; mm < 2; mm++)
        #pragma unroll
        for (int j = 0; j < 5; j++) o[mm][j] = {0.f, 0.f, 0.f, 0.f};

    const int nkt = 2 * qb + 2;
    // preamble: stage tile 0 into buf 0
    #pragma unroll
    for (int l = wave; l < 8; l += 4) {
        GLD16(K  + baseR + (size_t)(l * 8 + rg) * CH + cg * 8, &Ks[0][l * 512]);
        GLD16(Vt + baseV + (size_t)(l * 8 + rg) * SEQ + cg * 8, &Vs[0][l * 512]);
    }

    for (int kt = 0; kt < nkt; kt++) {
        __syncthreads();  // staging of kt landed; all waves done with buf kt^1
        const int cur = kt & 1;
        if (kt + 1 < nkt) {
            const int kv1 = (kt + 1) * 64, nb = cur ^ 1;
            #pragma unroll
            for (int l = wave; l < 8; l += 4) {
                GLD16(K  + baseR + (size_t)(kv1 + l * 8 + rg) * CH + cg * 8, &Ks[nb][l * 512]);
                GLD16(Vt + baseV + (size_t)(l * 8 + rg) * SEQ + kv1 + cg * 8, &Vs[nb][l * 512]);
            }
        }
        const int kv0 = kt * 64;
        const int masked = (kt >= 2 * qb);

        // K fragments shared by both q-groups: a-frag of S^T = K[kv][d]
        short8 kf[4][2];
        #pragma unroll
        for (int g = 0; g < 4; g++) {
            kf[g][0] = *(const short8*)&Ks[cur][(g * 16 + lane15) * 64 + ((quad ^ sw) * 8)];
            kf[g][1] = *(const short8*)&Ks[cur][(g * 16 + lane15) * 64 + (((quad + 4) ^ sw) * 8)];
        }

        #pragma unroll
        for (int mm = 0; mm < 2; mm++) {
            const int qrow = q0 + wave * 32 + mm * 16 + lane15;
            #pragma unroll
            for (int g = 0; g < 4; g++) {
                // z = S^T[kv = kv0+g*16+quad*4+r][q = qrow]
                floatx4 z = {0.f, 0.f, 0.f, 0.f};
                z = __builtin_amdgcn_mfma_f32_16x16x32_bf16(kf[g][0], qf[mm][0], z, 0, 0, 0);
                z = __builtin_amdgcn_mfma_f32_16x16x32_bf16(kf[g][1], qf[mm][1], z, 0, 0, 0);
                if (masked) {
                    #pragma unroll
                    for (int r = 0; r < 4; r++) {
                        const int col = kv0 + g * 16 + quad * 4 + r;
                        z[r] = (col <= qrow) ? z[r] : -1e30f;
                    }
                }
                // p = 2^z (2^-1e30 -> 0 for masked); pack 4 contiguous kv -> b64
                const float p0 = exp2f(z[0]), p1 = exp2f(z[1]);
                const float p2 = exp2f(z[2]), p3 = exp2f(z[3]);
                unsigned int lo, hi;
                asm("v_cvt_pk_bf16_f32 %0, %1, %2" : "=v"(lo) : "v"(p0), "v"(p1));
                asm("v_cvt_pk_bf16_f32 %0, %1, %2" : "=v"(hi) : "v"(p2), "v"(p3));
                uint2 w; w.x = lo; w.y = hi;
                *(uint2*)&Ps[wave * 2304 + (mm * 16 + lane15) * 72 + g * 16 + quad * 4] = w;
            }
        }
        // Ps wave-private: lgkmcnt auto-wait orders write->read, no barrier

        #pragma unroll
        for (int kk = 0; kk < 2; kk++) {
            #pragma unroll
            for (int mm = 0; mm < 2; mm++) {
                short8 a = *(const short8*)&Ps[wave * 2304 + (mm * 16 + lane15) * 72 + kk * 32 + quad * 8];
                #pragma unroll
                for (int jn = 0; jn < 4; jn++) {
                    short8 bb = *(const short8*)&Vs[cur][(jn * 16 + lane15) * 64 + (((kk * 4 + quad) ^ sw) * 8)];
                    o[mm][jn] = __builtin_amdgcn_mfma_f32_16x16x32_bf16(a, bb, o[mm][jn], 0, 0, 0);
                }
                o[mm][4] = __builtin_amdgcn_mfma_f32_16x16x32_bf16(a, kOnes, o[mm][4], 0, 0, 0);
            }
        }
    }

    // epilogue: Y = O / l
    #pragma unroll
    for (int mm = 0; mm < 2; mm++)
        #pragma unroll
        for (int r = 0; r < 4; r++) {
            const int qrow = q0 + wave * 32 + mm * 16 + quad * 4 + r;
            const float rinv = 1.0f / fmaxf(o[mm][4][r], 1e-30f);
            #pragma unroll
            for (int jn = 0; jn < 4; jn++)
                QY[baseR + (size_t)qrow * CH + jn * 16 + lane15] = f2b(o[mm][jn][r] * rinv);
        }
}

extern "C" void kernel_launch(void* const* d_in, const int* in_sizes, int n_in,
                              void* d_out, int out_size, void* d_ws, size_t ws_size,
                              hipStream_t stream) {
    const void* x  = d_in[0];
    const void* Wk = d_in[1];
    const void* bk = d_in[2];
    const void* Wq = d_in[3];
    const void* bq = d_in[4];
    const void* Wv = d_in[5];
    const void* bv = d_in[6];
    const void* Wo = d_in[7];
    const void* bo = d_in[8];

    ushort_t* ws    = (ushort_t*)d_ws;
    int*      flag  = (int*)d_ws;
    ushort_t* biasC = ws + 2048;                    // 4x1024: q,k,v,o (contiguous)
    ushort_t* WqkvT = ws + 32768;                   // 3x1M contiguous: q,k,v
    ushort_t* WoT   = WqkvT + 3u * (1u << 20);
    ushort_t* xb    = ws + 4227072;                 // 8M elems bf16
    ushort_t* Qb    = ws + 12615680;                // 8M elems (becomes Y)
    ushort_t* Kb    = (ushort_t*)d_out;             // d_out scratch until final GEMM
    ushort_t* VtB   = Kb + (size_t)MROWS * CH;

    detect_dtype<<<1, 64, 0, stream>>>((const ushort_t*)x, flag);

    dim3 tgrid(32, 32, 4);
    convert_wt4<<<tgrid, 256, 0, stream>>>(Wq, Wk, Wv, Wo,
                                           WqkvT, WqkvT + (1u << 20), WqkvT + 2u * (1u << 20), WoT, flag);
    convert_bias4<<<16, 256, 0, stream>>>(bq, bk, bv, bo, biasC, flag);
    convert_x<<<MROWS * CH / (256 * 8), 256, 0, stream>>>(x, xb, flag);

    // scale = (1/sqrt(64)) * log2(e), folded into Q so attention uses exp2
    dim3 qgrid(MROWS / 128, 3 * CH / 128);
    gemm_qkv<<<qgrid, 256, 0, stream>>>(xb, WqkvT, biasC, Qb, Kb, VtB, 0.1803368801f);

    attn_fwd<<<dim3(1024), 256, 0, stream>>>(Qb, Kb, VtB);

    dim3 ogrid(MROWS / 128, CH / 128);
    gemm_bt<<<ogrid, 256, 0, stream>>>(Qb, WoT, biasC + 3072, d_out, MROWS, CH, CH, flag);
}

// Round 2
// 247.876 us; speedup vs baseline: 1.0598x; 1.0380x over previous
//
#include <hip/hip_runtime.h>
#include <hip/hip_bf16.h>

typedef unsigned short ushort_t;
typedef __attribute__((ext_vector_type(8))) short short8;   // 8 x bf16 (4 VGPRs)
typedef __attribute__((ext_vector_type(4))) float floatx4;  // MFMA acc

#define BATCH 4
#define SEQ   2048
#define CH    1024
#define NHEAD 16
#define HSZ   64
#define MROWS (BATCH * SEQ)  // 8192

// async global->LDS, 16B per lane; LDS dest = wave-uniform base + lane*16
#define GLD16(gptr, lptr) \
    __builtin_amdgcn_global_load_lds((const __attribute__((address_space(1))) unsigned int*)(gptr), \
                                     (__attribute__((address_space(3))) unsigned int*)(lptr), 16, 0, 0)

__device__ inline ushort_t f2b(float f) {
    __hip_bfloat16 h = __float2bfloat16(f);
    return *(ushort_t*)&h;
}
__device__ inline float b2f(ushort_t u) {
    return __bfloat162float(*(__hip_bfloat16*)&u);
}

// raw v_exp_f32: OCML exp2f adds a denormal-range guard (~5 VALU insts/call)
// we don't need — masked inputs are -1e30 and raw v_exp_f32(-1e30) = +0.
__device__ __forceinline__ float fast_exp2(float x) {
#if __has_builtin(__builtin_amdgcn_exp2f)
    return __builtin_amdgcn_exp2f(x);
#else
    float r; asm("v_exp_f32 %0, %1" : "=v"(r) : "v"(x)); return r;
#endif
}

// -------- dtype detect (parallel): *flag = 1 if x is bf16, 0 if f32 --------------
__global__ void detect_dtype(const ushort_t* __restrict__ x, int* __restrict__ flag) {
    int cnt = 0;
    #pragma unroll
    for (int i = 0; i < 8; i++) {
        const int e = (x[2 * (threadIdx.x * 8 + i)] >> 7) & 0xFF;
        const unsigned long long m = __ballot(e >= 100 && e <= 140);
        cnt += (int)__popcll(m);
    }
    if (threadIdx.x == 0) *flag = (cnt >= 400) ? 1 : 0;
}

// -------- 4x weight transpose+convert: in[k][n] -> out bf16 [n][k] ---------------
__global__ __launch_bounds__(256) void convert_wt4(const void* w0, const void* w1,
                                                   const void* w2, const void* w3,
                                                   ushort_t* o0, ushort_t* o1,
                                                   ushort_t* o2, ushort_t* o3,
                                                   const int* __restrict__ flag) {
    __shared__ ushort_t tile[32][33];
    const void* in = (blockIdx.z == 0) ? w0 : (blockIdx.z == 1) ? w1 : (blockIdx.z == 2) ? w2 : w3;
    ushort_t*  out = (blockIdx.z == 0) ? o0 : (blockIdx.z == 1) ? o1 : (blockIdx.z == 2) ? o2 : o3;
    const int am = *flag;
    const int bx = blockIdx.x * 32, by = blockIdx.y * 32;
    const int tx = threadIdx.x & 31, ty = threadIdx.x >> 5;
    #pragma unroll
    for (int r = ty; r < 32; r += 8) {
        const size_t idx = (size_t)(by + r) * CH + bx + tx;
        tile[r][tx] = am ? ((const ushort_t*)in)[idx] : f2b(((const float*)in)[idx]);
    }
    __syncthreads();
    #pragma unroll
    for (int r = ty; r < 32; r += 8)
        out[(size_t)(bx + r) * CH + by + tx] = tile[tx][r];
}

// -------- 4x bias convert --------------------------------------------------------
__global__ void convert_bias4(const void* b0, const void* b1, const void* b2, const void* b3,
                              ushort_t* __restrict__ out, const int* __restrict__ flag) {
    const int i = blockIdx.x * 256 + threadIdx.x;  // 0..4095
    const int m = i >> 10, idx = i & 1023;
    const void* in = (m == 0) ? b0 : (m == 1) ? b1 : (m == 2) ? b2 : b3;
    out[i] = (*flag) ? ((const ushort_t*)in)[idx] : f2b(((const float*)in)[idx]);
}

// -------- x convert: flat fp32/bf16 -> bf16, 8 elems/thread ----------------------
__global__ __launch_bounds__(256) void convert_x(const void* __restrict__ in,
                                                 ushort_t* __restrict__ out,
                                                 const int* __restrict__ flag) {
    const int i = (blockIdx.x * 256 + threadIdx.x) * 8;
    if (*flag) {
        *(float4*)&out[i] = *(const float4*)&((const ushort_t*)in)[i];
    } else {
        const float* p = (const float*)in + i;
        float4 f0 = *(const float4*)p;
        float4 f1 = *(const float4*)(p + 4);
        ushort_t t[8] = {f2b(f0.x), f2b(f0.y), f2b(f0.z), f2b(f0.w),
                         f2b(f1.x), f2b(f1.y), f2b(f1.z), f2b(f1.w)};
        *(float4*)&out[i] = *(const float4*)t;
    }
}

// -------- BK=64 XOR-swizzled K-loop (shared by both GEMMs) -----------------------
// K=1024 -> 16 iterations (was 32): half the vmcnt(0)+barrier drains, 32 MFMA
// per iteration. 128-B LDS rows would be 16-way bank-conflicted on b128 frag
// reads, so staging XOR-permutes chunks: phys = logical ^ (row&7); reads use
// chunk (kk*4+quad)^(lane15&7) -> 2 lanes/bank = free (m136). LDS 2x16KB=32KB.
__device__ __forceinline__ void kloop64(const ushort_t* __restrict__ A,
                                        const ushort_t* __restrict__ Bt,
                                        int K, int row0, int col0,
                                        ushort_t* As, ushort_t* Bs,
                                        floatx4 acc[4][4],
                                        int lane, int wave) {
    const int lane15 = lane & 15, quad = lane >> 4;
    const int wr = (wave >> 1) * 64, wc = (wave & 1) * 64;
    const int rg = lane >> 3;                       // row within 8-row group
    const int cg = (lane & 7) ^ rg;                 // staged (permuted) chunk
    const int s7 = lane15 & 7;                      // read-side swizzle key
    for (int k0 = 0; k0 < K; k0 += 64) {
        #pragma unroll
        for (int l = wave; l < 16; l += 4) {        // 16 wave-loads each (8 rows x 1KB)
            GLD16(A  + (size_t)(row0 + l * 8 + rg) * K + k0 + cg * 8, &As[l * 512]);
            GLD16(Bt + (size_t)(col0 + l * 8 + rg) * K + k0 + cg * 8, &Bs[l * 512]);
        }
        __syncthreads();
        #pragma unroll
        for (int kk = 0; kk < 2; kk++) {
            short8 af[4], bfr[4];
            #pragma unroll
            for (int i = 0; i < 4; i++)
                af[i] = *(const short8*)&As[(wr + i * 16 + lane15) * 64 + (((kk * 4 + quad) ^ s7) * 8)];
            #pragma unroll
            for (int j = 0; j < 4; j++)
                bfr[j] = *(const short8*)&Bs[(wc + j * 16 + lane15) * 64 + (((kk * 4 + quad) ^ s7) * 8)];
            #pragma unroll
            for (int i = 0; i < 4; i++)
                #pragma unroll
                for (int j = 0; j < 4; j++)
                    acc[i][j] = __builtin_amdgcn_mfma_f32_16x16x32_bf16(af[i], bfr[j], acc[i][j], 0, 0, 0);
        }
        __syncthreads();
    }
}

// ---------------- fused QKV GEMM: [8192,1024] @ [3072,1024]^T + bias -------------
// Column segment (blockIdx.y>>3): 0 -> Qb row-major *qscale; 1 -> Kb row-major;
// 2 -> Vt[b][n][t] transposed-per-head. Branch is block-uniform.
__global__ __launch_bounds__(256) void gemm_qkv(const ushort_t* __restrict__ A,
                                                const ushort_t* __restrict__ Bt,
                                                const ushort_t* __restrict__ bias,
                                                ushort_t* __restrict__ Qb,
                                                ushort_t* __restrict__ Kb,
                                                ushort_t* __restrict__ Vt,
                                                float qscale) {
    __shared__ __align__(16) ushort_t As[128 * 64];
    __shared__ __align__(16) ushort_t Bs[128 * 64];
    const int tid = threadIdx.x;
    const int lane = tid & 63, wave = tid >> 6;
    const int lane15 = lane & 15, quad = lane >> 4;
    const int wr = (wave >> 1) * 64, wc = (wave & 1) * 64;
    const int row0 = blockIdx.x * 128, col0 = blockIdx.y * 128;
    const int seg = blockIdx.y >> 3;  // 0=Q 1=K 2=V

    floatx4 acc[4][4];
    #pragma unroll
    for (int i = 0; i < 4; i++)
        #pragma unroll
        for (int j = 0; j < 4; j++) acc[i][j] = {0.f, 0.f, 0.f, 0.f};

    kloop64(A, Bt, CH, row0, col0, As, Bs, acc, lane, wave);

    #pragma unroll
    for (int j = 0; j < 4; j++) {
        const int col = col0 + wc + j * 16 + lane15;
        const float bv = b2f(bias[col]);
        #pragma unroll
        for (int i = 0; i < 4; i++) {
            const int rowb = row0 + wr + i * 16 + quad * 4;
            if (seg == 0) {
                #pragma unroll
                for (int r = 0; r < 4; r++)
                    Qb[(size_t)(rowb + r) * CH + col] = f2b((acc[i][j][r] + bv) * qscale);
            } else if (seg == 1) {
                const int c = col - 1024;
                #pragma unroll
                for (int r = 0; r < 4; r++)
                    Kb[(size_t)(rowb + r) * CH + c] = f2b(acc[i][j][r] + bv);
            } else {
                const int c = col - 2048;
                ushort_t pk[4];
                #pragma unroll
                for (int r = 0; r < 4; r++) pk[r] = f2b(acc[i][j][r] + bv);
                const int bb = rowb >> 11, t = rowb & 2047;
                *(uint2*)&Vt[((size_t)bb * 1024 + c) * 2048 + t] = *(const uint2*)pk;
            }
        }
    }
}

// ---------------- output GEMM: Out[M,N] = A @ Bt^T + bias (fp32 or bf16 out) -----
__global__ __launch_bounds__(256) void gemm_bt(const ushort_t* __restrict__ A,
                                               const ushort_t* __restrict__ Bt,
                                               const ushort_t* __restrict__ bias,
                                               void* __restrict__ Out,
                                               int M, int N, int K,
                                               const int* __restrict__ oflag) {
    __shared__ __align__(16) ushort_t As[128 * 64];
    __shared__ __align__(16) ushort_t Bs[128 * 64];
    const int om = *oflag;
    const int tid = threadIdx.x;
    const int lane = tid & 63, wave = tid >> 6;
    const int lane15 = lane & 15, quad = lane >> 4;
    const int wr = (wave >> 1) * 64, wc = (wave & 1) * 64;
    const int row0 = blockIdx.x * 128, col0 = blockIdx.y * 128;

    floatx4 acc[4][4];
    #pragma unroll
    for (int i = 0; i < 4; i++)
        #pragma unroll
        for (int j = 0; j < 4; j++) acc[i][j] = {0.f, 0.f, 0.f, 0.f};

    kloop64(A, Bt, K, row0, col0, As, Bs, acc, lane, wave);

    #pragma unroll
    for (int j = 0; j < 4; j++) {
        const int col = col0 + wc + j * 16 + lane15;
        const float bv = b2f(bias[col]);
        #pragma unroll
        for (int i = 0; i < 4; i++) {
            const int rowb = row0 + wr + i * 16 + quad * 4;
            #pragma unroll
            for (int r = 0; r < 4; r++) {
                const float val = acc[i][j][r] + bv;
                const size_t idx = (size_t)(rowb + r) * N + col;
                if (om) ((ushort_t*)Out)[idx] = f2b(val);
                else    ((float*)Out)[idx] = val;
            }
        }
    }
}

// ---------------- flash attention (round-6 structure + S^T write path) -----------
// Keep: K/V dbuf, one barrier per tile, XCD-local (b,h) in bid&63, ones-MFMA
// rowsum, exp2 with scale folded into Q, swizzled K/V staging, Ps LDS round
// trip (decouples S from PV across waves). DO NOT add a second
// __launch_bounds__ arg (round-7 spill).
//
// R1 changes (post-mortem of R0's S^T write path):
// 1. fast_exp2 (raw v_exp_f32) replaces exp2f — OCML's denormal guard was
//    ~5 VALU insts x 32 calls/tile/lane, the dominant VALUBusy consumer.
// 2. Ps stride 72 -> 64 with 4-bit XOR chunk swizzle. Stride-72 made the R0
//    b64 writes 2-way bank-conflicted (dword = 4*lane15 mod 32; measured
//    +2.23M conflict cycles — matches 4 cyc x 8 wr x 4 waves x 17408 tiles).
//    Swizzle: physical 8B-chunk = logical-chunk ^ (row&15). b64 writes: 16
//    distinct chunks per 16-lane group -> 32 banks once -> free. PV reads
//    split b128 -> 2x b64 (swizzled chunks not adjacent): 16 distinct chunks
//    per group -> free. Ps 18KB -> 16KB (total LDS 48KB, 3 blocks/CU).
__global__ __launch_bounds__(256) void attn_fwd(ushort_t* __restrict__ QY,
                                                const ushort_t* __restrict__ K,
                                                const ushort_t* __restrict__ Vt) {
    __shared__ __align__(16) ushort_t Ks[2][64 * 64];    // [buf][kv][d], swizzled
    __shared__ __align__(16) ushort_t Vs[2][64 * 64];    // [buf][d][kv], swizzled
    __shared__ __align__(16) ushort_t Ps[4 * 32 * 64];   // per-wave [q=32][kv=64], XOR-swizzled
    const int tid = threadIdx.x;
    const int lane = tid & 63, wave = tid >> 6;
    const int lane15 = lane & 15, quad = lane >> 4;
    const int sw = lane15 & 7;                            // read-side swizzle key
    const int bid = blockIdx.x;
    const int hb = bid & 63, qslot = bid >> 6;
    const int qb = 15 - qslot;
    const int h = hb & 15, b = hb >> 4;
    const int q0 = qb * 128;
    const size_t baseR = (size_t)b * SEQ * CH + h * HSZ;      // +t*CH+d (Q,K,Y)
    const size_t baseV = ((size_t)b * 1024 + h * HSZ) * SEQ;  // +d*SEQ+t (Vt)
    const int rg = lane >> 3, cg = (lane & 7) ^ rg;           // staging swizzle
    const int psBase = wave * 2048;                           // per-wave Ps region

    short8 qf[2][2];
    #pragma unroll
    for (int mm = 0; mm < 2; mm++) {
        const ushort_t* qp = QY + baseR + (size_t)(q0 + wave * 32 + mm * 16 + lane15) * CH + quad * 8;
        qf[mm][0] = *(const short8*)qp;
        qf[mm][1] = *(const short8*)(qp + 32);
    }
    const short8 kOnes = (short8)(short)0x3F80;  // bf16 1.0 x8

    floatx4 o[2][5];  // [mm][0..3]=O d-chunks, [4]=l (rowsum)
    #pragma unroll
    for (int mm = 0; mm < 2; mm++)
        #pragma unroll
        for (int j = 0; j < 5; j++) o[mm][j] = {0.f, 0.f, 0.f, 0.f};

    const int nkt = 2 * qb + 2;
    // preamble: stage tile 0 into buf 0
    #pragma unroll
    for (int l = wave; l < 8; l += 4) {
        GLD16(K  + baseR + (size_t)(l * 8 + rg) * CH + cg * 8, &Ks[0][l * 512]);
        GLD16(Vt + baseV + (size_t)(l * 8 + rg) * SEQ + cg * 8, &Vs[0][l * 512]);
    }

    for (int kt = 0; kt < nkt; kt++) {
        __syncthreads();  // staging of kt landed; all waves done with buf kt^1
        const int cur = kt & 1;
        if (kt + 1 < nkt) {
            const int kv1 = (kt + 1) * 64, nb = cur ^ 1;
            #pragma unroll
            for (int l = wave; l < 8; l += 4) {
                GLD16(K  + baseR + (size_t)(kv1 + l * 8 + rg) * CH + cg * 8, &Ks[nb][l * 512]);
                GLD16(Vt + baseV + (size_t)(l * 8 + rg) * SEQ + kv1 + cg * 8, &Vs[nb][l * 512]);
            }
        }
        const int kv0 = kt * 64;
        const int masked = (kt >= 2 * qb);

        // K fragments shared by both q-groups: a-frag of S^T = K[kv][d]
        short8 kf[4][2];
        #pragma unroll
        for (int g = 0; g < 4; g++) {
            kf[g][0] = *(const short8*)&Ks[cur][(g * 16 + lane15) * 64 + ((quad ^ sw) * 8)];
            kf[g][1] = *(const short8*)&Ks[cur][(g * 16 + lane15) * 64 + (((quad + 4) ^ sw) * 8)];
        }

        #pragma unroll
        for (int mm = 0; mm < 2; mm++) {
            const int qrow = q0 + wave * 32 + mm * 16 + lane15;
            const int rowOff = psBase + (mm * 16 + lane15) * 64;
            #pragma unroll
            for (int g = 0; g < 4; g++) {
                // z = S^T[kv = kv0+g*16+quad*4+r][q = qrow]
                floatx4 z = {0.f, 0.f, 0.f, 0.f};
                z = __builtin_amdgcn_mfma_f32_16x16x32_bf16(kf[g][0], qf[mm][0], z, 0, 0, 0);
                z = __builtin_amdgcn_mfma_f32_16x16x32_bf16(kf[g][1], qf[mm][1], z, 0, 0, 0);
                if (masked) {
                    #pragma unroll
                    for (int r = 0; r < 4; r++) {
                        const int col = kv0 + g * 16 + quad * 4 + r;
                        z[r] = (col <= qrow) ? z[r] : -1e30f;
                    }
                }
                // p = 2^z (raw v_exp_f32: 2^-1e30 -> 0 for masked lanes)
                const float p0 = fast_exp2(z[0]), p1 = fast_exp2(z[1]);
                const float p2 = fast_exp2(z[2]), p3 = fast_exp2(z[3]);
                unsigned int lo, hi;
                asm("v_cvt_pk_bf16_f32 %0, %1, %2" : "=v"(lo) : "v"(p0), "v"(p1));
                asm("v_cvt_pk_bf16_f32 %0, %1, %2" : "=v"(hi) : "v"(p2), "v"(p3));
                uint2 w; w.x = lo; w.y = hi;
                // logical 8B-chunk c = g*4+quad; physical = c ^ (row&15)
                *(uint2*)&Ps[rowOff + (((g * 4 + quad) ^ lane15) * 4)] = w;
            }
        }
        // Ps wave-private: lgkmcnt auto-wait orders write->read, no barrier

        #pragma unroll
        for (int kk = 0; kk < 2; kk++) {
            #pragma unroll
            for (int mm = 0; mm < 2; mm++) {
                // A-frag: logical chunks c0 = kk*8+quad*2, c0+1; swizzled apart
                const int rowOff = psBase + (mm * 16 + lane15) * 64;
                const int c0 = kk * 8 + quad * 2;
                short8 a;
                ((uint2*)&a)[0] = *(const uint2*)&Ps[rowOff + (((c0    ) ^ lane15) * 4)];
                ((uint2*)&a)[1] = *(const uint2*)&Ps[rowOff + (((c0 + 1) ^ lane15) * 4)];
                #pragma unroll
                for (int jn = 0; jn < 4; jn++) {
                    short8 bb = *(const short8*)&Vs[cur][(jn * 16 + lane15) * 64 + (((kk * 4 + quad) ^ sw) * 8)];
                    o[mm][jn] = __builtin_amdgcn_mfma_f32_16x16x32_bf16(a, bb, o[mm][jn], 0, 0, 0);
                }
                o[mm][4] = __builtin_amdgcn_mfma_f32_16x16x32_bf16(a, kOnes, o[mm][4], 0, 0, 0);
            }
        }
    }

    // epilogue: Y = O / l
    #pragma unroll
    for (int mm = 0; mm < 2; mm++)
        #pragma unroll
        for (int r = 0; r < 4; r++) {
            const int qrow = q0 + wave * 32 + mm * 16 + quad * 4 + r;
            const float rinv = 1.0f / fmaxf(o[mm][4][r], 1e-30f);
            #pragma unroll
            for (int jn = 0; jn < 4; jn++)
                QY[baseR + (size_t)qrow * CH + jn * 16 + lane15] = f2b(o[mm][jn][r] * rinv);
        }
}

extern "C" void kernel_launch(void* const* d_in, const int* in_sizes, int n_in,
                              void* d_out, int out_size, void* d_ws, size_t ws_size,
                              hipStream_t stream) {
    const void* x  = d_in[0];
    const void* Wk = d_in[1];
    const void* bk = d_in[2];
    const void* Wq = d_in[3];
    const void* bq = d_in[4];
    const void* Wv = d_in[5];
    const void* bv = d_in[6];
    const void* Wo = d_in[7];
    const void* bo = d_in[8];

    ushort_t* ws    = (ushort_t*)d_ws;
    int*      flag  = (int*)d_ws;
    ushort_t* biasC = ws + 2048;                    // 4x1024: q,k,v,o (contiguous)
    ushort_t* WqkvT = ws + 32768;                   // 3x1M contiguous: q,k,v
    ushort_t* WoT   = WqkvT + 3u * (1u << 20);
    ushort_t* xb    = ws + 4227072;                 // 8M elems bf16
    ushort_t* Qb    = ws + 12615680;                // 8M elems (becomes Y)
    ushort_t* Kb    = (ushort_t*)d_out;             // d_out scratch until final GEMM
    ushort_t* VtB   = Kb + (size_t)MROWS * CH;

    detect_dtype<<<1, 64, 0, stream>>>((const ushort_t*)x, flag);

    dim3 tgrid(32, 32, 4);
    convert_wt4<<<tgrid, 256, 0, stream>>>(Wq, Wk, Wv, Wo,
                                           WqkvT, WqkvT + (1u << 20), WqkvT + 2u * (1u << 20), WoT, flag);
    convert_bias4<<<16, 256, 0, stream>>>(bq, bk, bv, bo, biasC, flag);
    convert_x<<<MROWS * CH / (256 * 8), 256, 0, stream>>>(x, xb, flag);

    // scale = (1/sqrt(64)) * log2(e), folded into Q so attention uses exp2
    dim3 qgrid(MROWS / 128, 3 * CH / 128);
    gemm_qkv<<<qgrid, 256, 0, stream>>>(xb, WqkvT, biasC, Qb, Kb, VtB, 0.1803368801f);

    attn_fwd<<<dim3(1024), 256, 0, stream>>>(Qb, Kb, VtB);

    dim3 ogrid(MROWS / 128, CH / 128);
    gemm_bt<<<ogrid, 256, 0, stream>>>(Qb, WoT, biasC + 3072, d_out, MROWS, CH, CH, flag);
}

// Round 3
// 246.333 us; speedup vs baseline: 1.0664x; 1.0063x over previous
//
#include <hip/hip_runtime.h>
#include <hip/hip_bf16.h>

typedef unsigned short ushort_t;
typedef __attribute__((ext_vector_type(8))) short short8;   // 8 x bf16 (4 VGPRs)
typedef __attribute__((ext_vector_type(4))) float floatx4;  // MFMA acc

#define BATCH 4
#define SEQ   2048
#define CH    1024
#define NHEAD 16
#define HSZ   64
#define MROWS (BATCH * SEQ)  // 8192

// async global->LDS, 16B per lane; LDS dest = wave-uniform base + lane*16
#define GLD16(gptr, lptr) \
    __builtin_amdgcn_global_load_lds((const __attribute__((address_space(1))) unsigned int*)(gptr), \
                                     (__attribute__((address_space(3))) unsigned int*)(lptr), 16, 0, 0)

__device__ inline ushort_t f2b(float f) {
    __hip_bfloat16 h = __float2bfloat16(f);
    return *(ushort_t*)&h;
}
__device__ inline float b2f(ushort_t u) {
    return __bfloat162float(*(__hip_bfloat16*)&u);
}

// raw v_exp_f32: OCML exp2f adds a denormal-range guard (~5 VALU insts/call)
// we don't need — masked inputs are -1e30 and raw v_exp_f32(-1e30) = +0.
__device__ __forceinline__ float fast_exp2(float x) {
#if __has_builtin(__builtin_amdgcn_exp2f)
    return __builtin_amdgcn_exp2f(x);
#else
    float r; asm("v_exp_f32 %0, %1" : "=v"(r) : "v"(x)); return r;
#endif
}

// -------- dtype detect (parallel): *flag = 1 if x is bf16, 0 if f32 --------------
__global__ void detect_dtype(const ushort_t* __restrict__ x, int* __restrict__ flag) {
    int cnt = 0;
    #pragma unroll
    for (int i = 0; i < 8; i++) {
        const int e = (x[2 * (threadIdx.x * 8 + i)] >> 7) & 0xFF;
        const unsigned long long m = __ballot(e >= 100 && e <= 140);
        cnt += (int)__popcll(m);
    }
    if (threadIdx.x == 0) *flag = (cnt >= 400) ? 1 : 0;
}

// -------- 4x weight transpose+convert: in[k][n] -> out bf16 [n][k] ---------------
__global__ __launch_bounds__(256) void convert_wt4(const void* w0, const void* w1,
                                                   const void* w2, const void* w3,
                                                   ushort_t* o0, ushort_t* o1,
                                                   ushort_t* o2, ushort_t* o3,
                                                   const int* __restrict__ flag) {
    __shared__ ushort_t tile[32][33];
    const void* in = (blockIdx.z == 0) ? w0 : (blockIdx.z == 1) ? w1 : (blockIdx.z == 2) ? w2 : w3;
    ushort_t*  out = (blockIdx.z == 0) ? o0 : (blockIdx.z == 1) ? o1 : (blockIdx.z == 2) ? o2 : o3;
    const int am = *flag;
    const int bx = blockIdx.x * 32, by = blockIdx.y * 32;
    const int tx = threadIdx.x & 31, ty = threadIdx.x >> 5;
    #pragma unroll
    for (int r = ty; r < 32; r += 8) {
        const size_t idx = (size_t)(by + r) * CH + bx + tx;
        tile[r][tx] = am ? ((const ushort_t*)in)[idx] : f2b(((const float*)in)[idx]);
    }
    __syncthreads();
    #pragma unroll
    for (int r = ty; r < 32; r += 8)
        out[(size_t)(bx + r) * CH + by + tx] = tile[tx][r];
}

// -------- 4x bias convert --------------------------------------------------------
__global__ void convert_bias4(const void* b0, const void* b1, const void* b2, const void* b3,
                              ushort_t* __restrict__ out, const int* __restrict__ flag) {
    const int i = blockIdx.x * 256 + threadIdx.x;  // 0..4095
    const int m = i >> 10, idx = i & 1023;
    const void* in = (m == 0) ? b0 : (m == 1) ? b1 : (m == 2) ? b2 : b3;
    out[i] = (*flag) ? ((const ushort_t*)in)[idx] : f2b(((const float*)in)[idx]);
}

// -------- x convert: flat fp32/bf16 -> bf16, 8 elems/thread ----------------------
__global__ __launch_bounds__(256) void convert_x(const void* __restrict__ in,
                                                 ushort_t* __restrict__ out,
                                                 const int* __restrict__ flag) {
    const int i = (blockIdx.x * 256 + threadIdx.x) * 8;
    if (*flag) {
        *(float4*)&out[i] = *(const float4*)&((const ushort_t*)in)[i];
    } else {
        const float* p = (const float*)in + i;
        float4 f0 = *(const float4*)p;
        float4 f1 = *(const float4*)(p + 4);
        ushort_t t[8] = {f2b(f0.x), f2b(f0.y), f2b(f0.z), f2b(f0.w),
                         f2b(f1.x), f2b(f1.y), f2b(f1.z), f2b(f1.w)};
        *(float4*)&out[i] = *(const float4*)t;
    }
}

// -------- BK=64 XOR-swizzled K-loop, double-buffered (shared by both GEMMs) ------
// R2: single-buffer + __syncthreads() drained vmcnt(0) every K-step — tile t+1
// loads could never overlap tile-t compute (MfmaUtil 28%, VALU 20%, HBM 20%,
// occupancy ~1.6 blocks/CU: latency-bound). Now: LDS double buffer (64KB, 2
// blocks/CU), issue next tile's 8 GLD16 per wave BEFORE compute, then
// s_waitcnt vmcnt(8) (the oldest 8 outstanding = tile t's) + raw s_barrier.
// Next-tile loads stay in flight across the whole MFMA phase (T3+T4). Last
// iteration peels to vmcnt(0). ds_read->MFMA lgkm waits remain compiler-
// managed (no inline-asm ds_reads -> no rule-18 hazard).
__device__ __forceinline__ void stage64(const ushort_t* __restrict__ A,
                                        const ushort_t* __restrict__ Bt,
                                        int K, int row0, int col0, int k0,
                                        ushort_t* As, ushort_t* Bs,
                                        int rg, int cg, int wave) {
    #pragma unroll
    for (int l = wave; l < 16; l += 4) {        // 8 GLD16 per wave per tile
        GLD16(A  + (size_t)(row0 + l * 8 + rg) * K + k0 + cg * 8, &As[l * 512]);
        GLD16(Bt + (size_t)(col0 + l * 8 + rg) * K + k0 + cg * 8, &Bs[l * 512]);
    }
}

__device__ __forceinline__ void kloop64(const ushort_t* __restrict__ A,
                                        const ushort_t* __restrict__ Bt,
                                        int K, int row0, int col0,
                                        ushort_t* As, ushort_t* Bs,   // [2][128*64] each
                                        floatx4 acc[4][4],
                                        int lane, int wave) {
    const int lane15 = lane & 15, quad = lane >> 4;
    const int wr = (wave >> 1) * 64, wc = (wave & 1) * 64;
    const int rg = lane >> 3;                       // row within 8-row group
    const int cg = (lane & 7) ^ rg;                 // staged (permuted) chunk
    const int s7 = lane15 & 7;                      // read-side swizzle key

    stage64(A, Bt, K, row0, col0, 0, As, Bs, rg, cg, wave);
    int cur = 0;
    for (int k0 = 0; k0 < K; k0 += 64) {
        if (k0 + 64 < K) {
            const int nb = cur ^ 1;
            stage64(A, Bt, K, row0, col0, k0 + 64, As + nb * 8192, Bs + nb * 8192, rg, cg, wave);
            asm volatile("s_waitcnt vmcnt(8)" ::: "memory");   // tile t's 8 landed; t+1 in flight
        } else {
            asm volatile("s_waitcnt vmcnt(0)" ::: "memory");   // final tile: drain
        }
        __builtin_amdgcn_s_barrier();                          // raw: no compiler vmcnt(0) drain
        const ushort_t* Ac = As + cur * 8192;
        const ushort_t* Bc = Bs + cur * 8192;
        #pragma unroll
        for (int kk = 0; kk < 2; kk++) {
            short8 af[4], bfr[4];
            #pragma unroll
            for (int i = 0; i < 4; i++)
                af[i] = *(const short8*)&Ac[(wr + i * 16 + lane15) * 64 + (((kk * 4 + quad) ^ s7) * 8)];
            #pragma unroll
            for (int j = 0; j < 4; j++)
                bfr[j] = *(const short8*)&Bc[(wc + j * 16 + lane15) * 64 + (((kk * 4 + quad) ^ s7) * 8)];
            #pragma unroll
            for (int i = 0; i < 4; i++)
                #pragma unroll
                for (int j = 0; j < 4; j++)
                    acc[i][j] = __builtin_amdgcn_mfma_f32_16x16x32_bf16(af[i], bfr[j], acc[i][j], 0, 0, 0);
        }
        __builtin_amdgcn_s_barrier();   // all waves done reading buf cur before it is re-staged
        cur ^= 1;
    }
}

// ---------------- fused QKV GEMM: [8192,1024] @ [3072,1024]^T + bias -------------
// Column segment (blockIdx.y>>3): 0 -> Qb row-major *qscale; 1 -> Kb row-major;
// 2 -> Vt[b][n][t] transposed-per-head. Branch is block-uniform.
__global__ __launch_bounds__(256) void gemm_qkv(const ushort_t* __restrict__ A,
                                                const ushort_t* __restrict__ Bt,
                                                const ushort_t* __restrict__ bias,
                                                ushort_t* __restrict__ Qb,
                                                ushort_t* __restrict__ Kb,
                                                ushort_t* __restrict__ Vt,
                                                float qscale) {
    __shared__ __align__(16) ushort_t As[2 * 128 * 64];
    __shared__ __align__(16) ushort_t Bs[2 * 128 * 64];
    const int tid = threadIdx.x;
    const int lane = tid & 63, wave = tid >> 6;
    const int lane15 = lane & 15, quad = lane >> 4;
    const int wr = (wave >> 1) * 64, wc = (wave & 1) * 64;
    const int row0 = blockIdx.x * 128, col0 = blockIdx.y * 128;
    const int seg = blockIdx.y >> 3;  // 0=Q 1=K 2=V

    floatx4 acc[4][4];
    #pragma unroll
    for (int i = 0; i < 4; i++)
        #pragma unroll
        for (int j = 0; j < 4; j++) acc[i][j] = {0.f, 0.f, 0.f, 0.f};

    kloop64(A, Bt, CH, row0, col0, As, Bs, acc, lane, wave);

    #pragma unroll
    for (int j = 0; j < 4; j++) {
        const int col = col0 + wc + j * 16 + lane15;
        const float bv = b2f(bias[col]);
        #pragma unroll
        for (int i = 0; i < 4; i++) {
            const int rowb = row0 + wr + i * 16 + quad * 4;
            if (seg == 0) {
                #pragma unroll
                for (int r = 0; r < 4; r++)
                    Qb[(size_t)(rowb + r) * CH + col] = f2b((acc[i][j][r] + bv) * qscale);
            } else if (seg == 1) {
                const int c = col - 1024;
                #pragma unroll
                for (int r = 0; r < 4; r++)
                    Kb[(size_t)(rowb + r) * CH + c] = f2b(acc[i][j][r] + bv);
            } else {
                const int c = col - 2048;
                ushort_t pk[4];
                #pragma unroll
                for (int r = 0; r < 4; r++) pk[r] = f2b(acc[i][j][r] + bv);
                const int bb = rowb >> 11, t = rowb & 2047;
                *(uint2*)&Vt[((size_t)bb * 1024 + c) * 2048 + t] = *(const uint2*)pk;
            }
        }
    }
}

// ---------------- output GEMM: Out[M,N] = A @ Bt^T + bias (fp32 or bf16 out) -----
__global__ __launch_bounds__(256) void gemm_bt(const ushort_t* __restrict__ A,
                                               const ushort_t* __restrict__ Bt,
                                               const ushort_t* __restrict__ bias,
                                               void* __restrict__ Out,
                                               int M, int N, int K,
                                               const int* __restrict__ oflag) {
    __shared__ __align__(16) ushort_t As[2 * 128 * 64];
    __shared__ __align__(16) ushort_t Bs[2 * 128 * 64];
    const int om = *oflag;
    const int tid = threadIdx.x;
    const int lane = tid & 63, wave = tid >> 6;
    const int lane15 = lane & 15, quad = lane >> 4;
    const int wr = (wave >> 1) * 64, wc = (wave & 1) * 64;
    const int row0 = blockIdx.x * 128, col0 = blockIdx.y * 128;

    floatx4 acc[4][4];
    #pragma unroll
    for (int i = 0; i < 4; i++)
        #pragma unroll
        for (int j = 0; j < 4; j++) acc[i][j] = {0.f, 0.f, 0.f, 0.f};

    kloop64(A, Bt, K, row0, col0, As, Bs, acc, lane, wave);

    #pragma unroll
    for (int j = 0; j < 4; j++) {
        const int col = col0 + wc + j * 16 + lane15;
        const float bv = b2f(bias[col]);
        #pragma unroll
        for (int i = 0; i < 4; i++) {
            const int rowb = row0 + wr + i * 16 + quad * 4;
            #pragma unroll
            for (int r = 0; r < 4; r++) {
                const float val = acc[i][j][r] + bv;
                const size_t idx = (size_t)(rowb + r) * N + col;
                if (om) ((ushort_t*)Out)[idx] = f2b(val);
                else    ((float*)Out)[idx] = val;
            }
        }
    }
}

// ---------------- flash attention (round-6 structure + S^T write path) -----------
// Keep: K/V dbuf, one barrier per tile, XCD-local (b,h) in bid&63, ones-MFMA
// rowsum, exp2 with scale folded into Q, swizzled K/V staging, Ps LDS round
// trip (decouples S from PV across waves). DO NOT add a second
// __launch_bounds__ arg (round-7 spill).
//
// R1 (kept): fast_exp2 raw v_exp_f32; Ps stride-64 4-bit XOR chunk swizzle
// (b64 writes and split-b64 PV reads both bank-conflict-free). Verified R2:
// attn dropped out of top-5 (<71.5 us, was 75.5).
__global__ __launch_bounds__(256) void attn_fwd(ushort_t* __restrict__ QY,
                                                const ushort_t* __restrict__ K,
                                                const ushort_t* __restrict__ Vt) {
    __shared__ __align__(16) ushort_t Ks[2][64 * 64];    // [buf][kv][d], swizzled
    __shared__ __align__(16) ushort_t Vs[2][64 * 64];    // [buf][d][kv], swizzled
    __shared__ __align__(16) ushort_t Ps[4 * 32 * 64];   // per-wave [q=32][kv=64], XOR-swizzled
    const int tid = threadIdx.x;
    const int lane = tid & 63, wave = tid >> 6;
    const int lane15 = lane & 15, quad = lane >> 4;
    const int sw = lane15 & 7;                            // read-side swizzle key
    const int bid = blockIdx.x;
    const int hb = bid & 63, qslot = bid >> 6;
    const int qb = 15 - qslot;
    const int h = hb & 15, b = hb >> 4;
    const int q0 = qb * 128;
    const size_t baseR = (size_t)b * SEQ * CH + h * HSZ;      // +t*CH+d (Q,K,Y)
    const size_t baseV = ((size_t)b * 1024 + h * HSZ) * SEQ;  // +d*SEQ+t (Vt)
    const int rg = lane >> 3, cg = (lane & 7) ^ rg;           // staging swizzle
    const int psBase = wave * 2048;                           // per-wave Ps region

    short8 qf[2][2];
    #pragma unroll
    for (int mm = 0; mm < 2; mm++) {
        const ushort_t* qp = QY + baseR + (size_t)(q0 + wave * 32 + mm * 16 + lane15) * CH + quad * 8;
        qf[mm][0] = *(const short8*)qp;
        qf[mm][1] = *(const short8*)(qp + 32);
    }
    const short8 kOnes = (short8)(short)0x3F80;  // bf16 1.0 x8

    floatx4 o[2][5];  // [mm][0..3]=O d-chunks, [4]=l (rowsum)
    #pragma unroll
    for (int mm = 0; mm < 2; mm++)
        #pragma unroll
        for (int j = 0; j < 5; j++) o[mm][j] = {0.f, 0.f, 0.f, 0.f};

    const int nkt = 2 * qb + 2;
    // preamble: stage tile 0 into buf 0
    #pragma unroll
    for (int l = wave; l < 8; l += 4) {
        GLD16(K  + baseR + (size_t)(l * 8 + rg) * CH + cg * 8, &Ks[0][l * 512]);
        GLD16(Vt + baseV + (size_t)(l * 8 + rg) * SEQ + cg * 8, &Vs[0][l * 512]);
    }

    for (int kt = 0; kt < nkt; kt++) {
        __syncthreads();  // staging of kt landed; all waves done with buf kt^1
        const int cur = kt & 1;
        if (kt + 1 < nkt) {
            const int kv1 = (kt + 1) * 64, nb = cur ^ 1;
            #pragma unroll
            for (int l = wave; l < 8; l += 4) {
                GLD16(K  + baseR + (size_t)(kv1 + l * 8 + rg) * CH + cg * 8, &Ks[nb][l * 512]);
                GLD16(Vt + baseV + (size_t)(l * 8 + rg) * SEQ + kv1 + cg * 8, &Vs[nb][l * 512]);
            }
        }
        const int kv0 = kt * 64;
        const int masked = (kt >= 2 * qb);

        // K fragments shared by both q-groups: a-frag of S^T = K[kv][d]
        short8 kf[4][2];
        #pragma unroll
        for (int g = 0; g < 4; g++) {
            kf[g][0] = *(const short8*)&Ks[cur][(g * 16 + lane15) * 64 + ((quad ^ sw) * 8)];
            kf[g][1] = *(const short8*)&Ks[cur][(g * 16 + lane15) * 64 + (((quad + 4) ^ sw) * 8)];
        }

        #pragma unroll
        for (int mm = 0; mm < 2; mm++) {
            const int qrow = q0 + wave * 32 + mm * 16 + lane15;
            const int rowOff = psBase + (mm * 16 + lane15) * 64;
            #pragma unroll
            for (int g = 0; g < 4; g++) {
                // z = S^T[kv = kv0+g*16+quad*4+r][q = qrow]
                floatx4 z = {0.f, 0.f, 0.f, 0.f};
                z = __builtin_amdgcn_mfma_f32_16x16x32_bf16(kf[g][0], qf[mm][0], z, 0, 0, 0);
                z = __builtin_amdgcn_mfma_f32_16x16x32_bf16(kf[g][1], qf[mm][1], z, 0, 0, 0);
                if (masked) {
                    #pragma unroll
                    for (int r = 0; r < 4; r++) {
                        const int col = kv0 + g * 16 + quad * 4 + r;
                        z[r] = (col <= qrow) ? z[r] : -1e30f;
                    }
                }
                // p = 2^z (raw v_exp_f32: 2^-1e30 -> 0 for masked lanes)
                const float p0 = fast_exp2(z[0]), p1 = fast_exp2(z[1]);
                const float p2 = fast_exp2(z[2]), p3 = fast_exp2(z[3]);
                unsigned int lo, hi;
                asm("v_cvt_pk_bf16_f32 %0, %1, %2" : "=v"(lo) : "v"(p0), "v"(p1));
                asm("v_cvt_pk_bf16_f32 %0, %1, %2" : "=v"(hi) : "v"(p2), "v"(p3));
                uint2 w; w.x = lo; w.y = hi;
                // logical 8B-chunk c = g*4+quad; physical = c ^ (row&15)
                *(uint2*)&Ps[rowOff + (((g * 4 + quad) ^ lane15) * 4)] = w;
            }
        }
        // Ps wave-private: lgkmcnt auto-wait orders write->read, no barrier

        #pragma unroll
        for (int kk = 0; kk < 2; kk++) {
            #pragma unroll
            for (int mm = 0; mm < 2; mm++) {
                // A-frag: logical chunks c0 = kk*8+quad*2, c0+1; swizzled apart
                const int rowOff = psBase + (mm * 16 + lane15) * 64;
                const int c0 = kk * 8 + quad * 2;
                short8 a;
                ((uint2*)&a)[0] = *(const uint2*)&Ps[rowOff + (((c0    ) ^ lane15) * 4)];
                ((uint2*)&a)[1] = *(const uint2*)&Ps[rowOff + (((c0 + 1) ^ lane15) * 4)];
                #pragma unroll
                for (int jn = 0; jn < 4; jn++) {
                    short8 bb = *(const short8*)&Vs[cur][(jn * 16 + lane15) * 64 + (((kk * 4 + quad) ^ sw) * 8)];
                    o[mm][jn] = __builtin_amdgcn_mfma_f32_16x16x32_bf16(a, bb, o[mm][jn], 0, 0, 0);
                }
                o[mm][4] = __builtin_amdgcn_mfma_f32_16x16x32_bf16(a, kOnes, o[mm][4], 0, 0, 0);
            }
        }
    }

    // epilogue: Y = O / l
    #pragma unroll
    for (int mm = 0; mm < 2; mm++)
        #pragma unroll
        for (int r = 0; r < 4; r++) {
            const int qrow = q0 + wave * 32 + mm * 16 + quad * 4 + r;
            const float rinv = 1.0f / fmaxf(o[mm][4][r], 1e-30f);
            #pragma unroll
            for (int jn = 0; jn < 4; jn++)
                QY[baseR + (size_t)qrow * CH + jn * 16 + lane15] = f2b(o[mm][jn][r] * rinv);
        }
}

extern "C" void kernel_launch(void* const* d_in, const int* in_sizes, int n_in,
                              void* d_out, int out_size, void* d_ws, size_t ws_size,
                              hipStream_t stream) {
    const void* x  = d_in[0];
    const void* Wk = d_in[1];
    const void* bk = d_in[2];
    const void* Wq = d_in[3];
    const void* bq = d_in[4];
    const void* Wv = d_in[5];
    const void* bv = d_in[6];
    const void* Wo = d_in[7];
    const void* bo = d_in[8];

    ushort_t* ws    = (ushort_t*)d_ws;
    int*      flag  = (int*)d_ws;
    ushort_t* biasC = ws + 2048;                    // 4x1024: q,k,v,o (contiguous)
    ushort_t* WqkvT = ws + 32768;                   // 3x1M contiguous: q,k,v
    ushort_t* WoT   = WqkvT + 3u * (1u << 20);
    ushort_t* xb    = ws + 4227072;                 // 8M elems bf16
    ushort_t* Qb    = ws + 12615680;                // 8M elems (becomes Y)
    ushort_t* Kb    = (ushort_t*)d_out;             // d_out scratch until final GEMM
    ushort_t* VtB   = Kb + (size_t)MROWS * CH;

    detect_dtype<<<1, 64, 0, stream>>>((const ushort_t*)x, flag);

    dim3 tgrid(32, 32, 4);
    convert_wt4<<<tgrid, 256, 0, stream>>>(Wq, Wk, Wv, Wo,
                                           WqkvT, WqkvT + (1u << 20), WqkvT + 2u * (1u << 20), WoT, flag);
    convert_bias4<<<16, 256, 0, stream>>>(bq, bk, bv, bo, biasC, flag);
    convert_x<<<MROWS * CH / (256 * 8), 256, 0, stream>>>(x, xb, flag);

    // scale = (1/sqrt(64)) * log2(e), folded into Q so attention uses exp2
    dim3 qgrid(MROWS / 128, 3 * CH / 128);
    gemm_qkv<<<qgrid, 256, 0, stream>>>(xb, WqkvT, biasC, Qb, Kb, VtB, 0.1803368801f);

    attn_fwd<<<dim3(1024), 256, 0, stream>>>(Qb, Kb, VtB);

    dim3 ogrid(MROWS / 128, CH / 128);
    gemm_bt<<<ogrid, 256, 0, stream>>>(Qb, WoT, biasC + 3072, d_out, MROWS, CH, CH, flag);
}